// Round 8
// baseline (79.844 us; speedup 1.0000x reference)
//
#include <hip/hip_runtime.h>

// Radon3D loss on MI355X — project the DIFFERENCE volume (radon is linear).
// Geometry (D=H=W=64, 120 angles over [0,120] deg): L=91, pad top=left=13.
//   ix(i,j) = 45*c*linj + 32 + 45*s - s*i,  iy(i,j) = 45*s*linj + 32 - 45*c + c*i
//   (unit steps in i: the 0.5*(L-1) unnormalization cancels the linspace step)
// FP8 (OCP e4m3) canvas: cell = 16 B = [8-slice fp8 pack @ (y,x) | pack @
// (y,x+1)] (x-neighbor duplicated). 2 x ds_read_b128 fetch all 16 corner
// packs for EIGHT slices -> LDS bytes/slice-sample halve vs R7 (the measured
// bottleneck). Diffs are in (-1,1): e4m3 quant noise ~0.01/px, random-sign,
// cancels in the 698k-entry loss mean (threshold 2.09).
// Coords shifted +1 (nonneg), clamped to [0,65]: out-of-support samples hit
// the zero border with zero weight == map_coordinates mode='constant' cval=0.
#define DD 64
#define NA 120
#define LL 91
#define PS 67
#define PSTR 69               // cell stride per row
#define NCELL (PS * PSTR)     // 4623 cells * 16 B = 74.0 KB
#define NSL 8                 // slices per block (one fp8 byte-lane each)
#define NANG 4                // angles per block
#define JT 96                 // j-lanes per angle (91 active)
#define NTHR (NANG * JT)      // 384 threads = 6 waves
#define NSP (64 / NSL)        // 8 slice groups
#define NAP (NA / NANG)       // 30 angle groups
#define NBLKS (NSP * NAP)     // 240 blocks

typedef float f32x2 __attribute__((ext_vector_type(2)));

__global__ __launch_bounds__(NTHR, 2) void radon_loss_kernel(
    const float* __restrict__ vout, const float* __restrict__ vgt,
    float* __restrict__ out)
{
    __shared__ uint4 C[NCELL];           // wide fp8 canvas, 74 KB
    __shared__ float wsum[NTHR / 64];

    const int bid = blockIdx.x;
    const int sp = bid / NAP;            // slice group 0..7
    const int ap = bid - sp * NAP;       // angle group 0..29
    const int s0 = sp * NSL;
    const int t = threadIdx.x;

    // 1) zero the padded wide canvas
    for (int idx = t; idx < NCELL; idx += NTHR)
        C[idx] = make_uint4(0u, 0u, 0u, 0u);
    __syncthreads();

    // 2) stage fp8 diffs of 8 slices. Pixel (d,w) -> 8 B pack, written to
    //    cell(d+1, w+1) dwords 0,1 ("x" entry) and cell(d+1, w) dwords 2,3
    //    ("x+1" entry). Disjoint 8 B halves -> no write races.
    for (int idx = t; idx < DD * DD; idx += NTHR) {
        const int d = idx >> 6, w = idx & 63;
        const int g = d * 4096 + s0 * 64 + w;
        float df[NSL];
        #pragma unroll
        for (int k = 0; k < NSL; ++k)
            df[k] = vout[g + 64 * k] - vgt[g + 64 * k];
        int p0 = 0, p1 = 0;
        p0 = __builtin_amdgcn_cvt_pk_fp8_f32(df[0], df[1], p0, false);
        p0 = __builtin_amdgcn_cvt_pk_fp8_f32(df[2], df[3], p0, true);
        p1 = __builtin_amdgcn_cvt_pk_fp8_f32(df[4], df[5], p1, false);
        p1 = __builtin_amdgcn_cvt_pk_fp8_f32(df[6], df[7], p1, true);
        const int rb = (d + 1) * PSTR + w;
        ((uint2*)&C[rb + 1])[0] = make_uint2((unsigned)p0, (unsigned)p1);
        ((uint2*)&C[rb])[1]     = make_uint2((unsigned)p0, (unsigned)p1);
    }
    __syncthreads();

    // 3) projection: thread = (angle slot, column j); full i-range per thread
    const int ja = t / JT;
    const int j  = t - ja * JT;
    const int a  = ap * NANG + ja;
    const float theta = (float)a * (float)(3.14159265358979323846 * 120.0 / 119.0 / 180.0);
    const float c = cosf(theta), sn = sinf(theta);

    float val = 0.f;
    if (j < LL) {
        const float linj = fmaf((float)j, 2.0f / 90.0f, -1.0f);
        // +1 shift: coords in [0,65] after clamp; canvas row/col 0 is border
        const float bx1 = fmaf(c,  linj, 1.0f) * 45.0f - 12.0f + 45.0f * sn;
        const float by1 = fmaf(sn, linj, 1.0f) * 45.0f - 12.0f - 45.0f * c;
        float a0 = 0.f, a1 = 0.f, a2 = 0.f, a3 = 0.f;
        float a4 = 0.f, a5 = 0.f, a6 = 0.f, a7 = 0.f;
        #pragma unroll 7
        for (int i = 0; i < LL; ++i) {
            // independent per-iteration coords -> deep ILP under unroll
            const float xs = fminf(fmaxf(fmaf(-(float)i, sn, bx1), 0.0f), 65.0f);
            const float ys = fminf(fmaxf(fmaf( (float)i, c,  by1), 0.0f), 65.0f);
            const int ix = (int)xs;            // trunc == floor (nonneg)
            const int iy = (int)ys;
            const float wx = __builtin_amdgcn_fractf(xs);
            const float wy = __builtin_amdgcn_fractf(ys);
            const float ux = 1.f - wx, uy = 1.f - wy;
            const float w00 = ux * uy, w01 = wx * uy;
            const float w10 = ux * wy, w11 = wx * wy;
            const int ci = iy * PSTR + ix;
            const uint4 q0 = C[ci];            // row y  : [D(x)8 | D(x+1)8]
            const uint4 q1 = C[ci + PSTR];     // row y+1: [D(x)8 | D(x+1)8]
            // slices 0-3 (dword 0 of each pack)
            {
                const f32x2 vA = __builtin_amdgcn_cvt_pk_f32_fp8(q0.x, false);
                const f32x2 vB = __builtin_amdgcn_cvt_pk_f32_fp8(q0.x, true);
                const f32x2 vC = __builtin_amdgcn_cvt_pk_f32_fp8(q0.z, false);
                const f32x2 vD = __builtin_amdgcn_cvt_pk_f32_fp8(q0.z, true);
                const f32x2 vE = __builtin_amdgcn_cvt_pk_f32_fp8(q1.x, false);
                const f32x2 vF = __builtin_amdgcn_cvt_pk_f32_fp8(q1.x, true);
                const f32x2 vG = __builtin_amdgcn_cvt_pk_f32_fp8(q1.z, false);
                const f32x2 vH = __builtin_amdgcn_cvt_pk_f32_fp8(q1.z, true);
                a0 = fmaf(w00, vA.x, fmaf(w01, vC.x, fmaf(w10, vE.x, fmaf(w11, vG.x, a0))));
                a1 = fmaf(w00, vA.y, fmaf(w01, vC.y, fmaf(w10, vE.y, fmaf(w11, vG.y, a1))));
                a2 = fmaf(w00, vB.x, fmaf(w01, vD.x, fmaf(w10, vF.x, fmaf(w11, vH.x, a2))));
                a3 = fmaf(w00, vB.y, fmaf(w01, vD.y, fmaf(w10, vF.y, fmaf(w11, vH.y, a3))));
            }
            // slices 4-7 (dword 1 of each pack)
            {
                const f32x2 vA = __builtin_amdgcn_cvt_pk_f32_fp8(q0.y, false);
                const f32x2 vB = __builtin_amdgcn_cvt_pk_f32_fp8(q0.y, true);
                const f32x2 vC = __builtin_amdgcn_cvt_pk_f32_fp8(q0.w, false);
                const f32x2 vD = __builtin_amdgcn_cvt_pk_f32_fp8(q0.w, true);
                const f32x2 vE = __builtin_amdgcn_cvt_pk_f32_fp8(q1.y, false);
                const f32x2 vF = __builtin_amdgcn_cvt_pk_f32_fp8(q1.y, true);
                const f32x2 vG = __builtin_amdgcn_cvt_pk_f32_fp8(q1.w, false);
                const f32x2 vH = __builtin_amdgcn_cvt_pk_f32_fp8(q1.w, true);
                a4 = fmaf(w00, vA.x, fmaf(w01, vC.x, fmaf(w10, vE.x, fmaf(w11, vG.x, a4))));
                a5 = fmaf(w00, vA.y, fmaf(w01, vC.y, fmaf(w10, vE.y, fmaf(w11, vG.y, a5))));
                a6 = fmaf(w00, vB.x, fmaf(w01, vD.x, fmaf(w10, vF.x, fmaf(w11, vH.x, a6))));
                a7 = fmaf(w00, vB.y, fmaf(w01, vD.y, fmaf(w10, vF.y, fmaf(w11, vH.y, a7))));
            }
        }
        val = fabsf(a0) + fabsf(a1) + fabsf(a2) + fabsf(a3)
            + fabsf(a4) + fabsf(a5) + fabsf(a6) + fabsf(a7);
    }

    // 4) block reduction + one scaled atomic per block
    #pragma unroll
    for (int off = 32; off > 0; off >>= 1)
        val += __shfl_down(val, off);
    const int wave = t >> 6, lane = t & 63;
    if (lane == 0) wsum[wave] = val;
    __syncthreads();
    if (t == 0) {
        float v = 0.f;
        #pragma unroll
        for (int wv = 0; wv < NTHR / 64; ++wv) v += wsum[wv];
        atomicAdd(out, v * (1.0f / (float)(NA * LL)));
    }
}

extern "C" void kernel_launch(void* const* d_in, const int* in_sizes, int n_in,
                              void* d_out, int out_size, void* d_ws, size_t ws_size,
                              hipStream_t stream) {
    const float* vout = (const float*)d_in[0];
    const float* vgt  = (const float*)d_in[1];
    float* out = (float*)d_out;

    hipMemsetAsync(out, 0, sizeof(float), stream);
    radon_loss_kernel<<<NBLKS, NTHR, 0, stream>>>(vout, vgt, out);
}